// Round 5
// baseline (1617.200 us; speedup 1.0000x reference)
//
#include <hip/hip_runtime.h>
#include <hip/hip_bf16.h>

// 2-layer tanh RNN. B=256, T=1024, H=128, V=96. x int32; float tensors fp32
// (runtime-detected, r3/r4: fp32 path taken and passing).
// d_out: out[B*T,96] ++ hidden[2,B,128]

#define B_SZ 256
#define T_LEN 1024
#define HD 128
#define VC 96
#define OUT_MAIN (B_SZ * T_LEN * VC)
#define HID_OFF OUT_MAIN

// padded h layout: chunk c (16 floats) at float-offset 20c → conflict-free.
#define HPAD(k) ((k) + 4 * ((k) >> 4))
#define HP_SZ 160

typedef float v16f __attribute__((ext_vector_type(16)));

// DPP lane-swap controls
#define DPP_QP_XOR1 0xB1      // quad_perm(1,0,3,2)
#define DPP_QP_XOR2 0x4E      // quad_perm(2,3,0,1)
#define DPP_HALF_MIRROR 0x141 // mirror within 8 lanes

template <int CTRL>
__device__ __forceinline__ float dpp_f(float x) {
  union { float f; int i; } a, r;
  a.f = x;
  r.i = __builtin_amdgcn_update_dpp(0, a.i, CTRL, 0xF, 0xF, true);
  return r.f;
}

__device__ __forceinline__ float bf2f(__hip_bfloat16 v) { return __bfloat162float(v); }

__device__ __forceinline__ bool detect_f32(const void* p) {
  const unsigned short* u = (const unsigned short*)p;
  int hits = 0;
#pragma unroll
  for (int i = 0; i < 128; ++i) hits += (((u[i] >> 7) & 0xFF) >= 127);
  return hits > 2;
}

__device__ __forceinline__ float ldw(const void* p, int i, bool f32) {
  return f32 ? ((const float*)p)[i] : bf2f(((const __hip_bfloat16*)p)[i]);
}

__device__ __forceinline__ float tanh_fast(float x) {
  float ax = fabsf(x);
  float e = __expf(-2.0f * ax);
  float y = 1.0f - 2.0f * __fdividef(e, 1.0f + e);
  return copysignf(y, x);
}

__global__ __launch_bounds__(128) void embp_kernel(
    const void* __restrict__ emb, const void* __restrict__ Wih0,
    const void* __restrict__ bih0, const void* __restrict__ bhh0,
    float* __restrict__ embp) {
  const bool f32 = detect_f32(emb);
  __shared__ float ev[HD];
  const int v = blockIdx.x, r = threadIdx.x;
  ev[r] = ldw(emb, v * HD + r, f32);
  __syncthreads();
  float acc = ldw(bih0, r, f32) + ldw(bhh0, r, f32);
#pragma unroll 8
  for (int j = 0; j < HD; ++j) acc += ldw(Wih0, r * HD + j, f32) * ev[j];
  embp[v * HD + r] = acc;
}

// One block = one batch sequence. 512 threads = 8 waves (2/SIMD).
// s = tid&7 owns K-chunk [16s,16s+16) in every phase (register carry).
// SPLIT: FC moved to epilogue; h1 streamed to h1hist.
template <bool USE_WS, bool SPLIT>
__global__ __launch_bounds__(512, 2) void rnn_fused(
    const int* __restrict__ x,
    const float* __restrict__ embp_g,
    const void* __restrict__ emb,
    const void* __restrict__ Wih0,
    const void* __restrict__ bih0,
    const void* __restrict__ bhh0,
    const void* __restrict__ Whh0,
    const void* __restrict__ Wih1,
    const void* __restrict__ Whh1,
    const void* __restrict__ bih1,
    const void* __restrict__ bhh1,
    const void* __restrict__ fcW,
    const void* __restrict__ fcb_g,
    float* __restrict__ h1hist,
    void* __restrict__ out) {
  __shared__ __align__(16) float embp[VC * HD];
  __shared__ __align__(16) float h0p[HP_SZ];
  __shared__ __align__(16) float h1p[HP_SZ];
  __shared__ __align__(16) float r1buf[HD];
  __shared__ __align__(16) float xb1[HD];
  __shared__ __align__(16) float fcb[VC];
  __shared__ __align__(16) int xrow[T_LEN];

  const int tid = threadIdx.x;
  const int b = blockIdx.x;
  const bool f32 = detect_f32(emb);

  xrow[tid] = x[b * T_LEN + tid];
  xrow[tid + 512] = x[b * T_LEN + 512 + tid];

  if constexpr (USE_WS) {
    const float4* src = (const float4*)embp_g;
    float4* dst = (float4*)embp;
#pragma unroll
    for (int i = 0; i < (VC * HD / 4) / 512; ++i) dst[tid + i * 512] = src[tid + i * 512];
  } else {
    const int r = tid & 127, vg = tid >> 7;
    const float bsum = ldw(bih0, r, f32) + ldw(bhh0, r, f32);
    for (int vi = 0; vi < 24; ++vi) {
      const int v = vg * 24 + vi;
      float acc = bsum;
#pragma unroll 8
      for (int k = 0; k < HD; ++k)
        acc += ldw(Wih0, r * HD + k, f32) * ldw(emb, v * HD + k, f32);
      embp[v * HD + r] = acc;
    }
  }

  if (tid < HD) xb1[tid] = ldw(bih1, tid, f32) + ldw(bhh1, tid, f32);
  if (tid < VC) fcb[tid] = ldw(fcb_g, tid, f32);

  // ---- thread roles ----
  const int s = tid & 7;
  const int m1 = tid >> 8;            // wave-uniform: 0=layer0, 1=layer1 in P1
  const int g = (tid >> 3) & 31;      // P1 rows 4g..4g+3
  const int G = tid >> 3;             // P2 rows 2G,2G+1 (G<64)
  const int s1b = s & 1, s2b = (s >> 1) & 1;
  const int permrow = ((s & 1) << 1) | ((s >> 1) & 1);

  // ---- weights as vector values (push arch-VGPR residency) ----
  v16f w1r0, w1r1, w1r2, w1r3;
  {
    const void* W = m1 ? Whh1 : Whh0;
    const int rb = 4 * g, cb = 16 * s;
#pragma unroll
    for (int j = 0; j < 16; ++j) {
      w1r0[j] = ldw(W, (rb + 0) * HD + cb + j, f32);
      w1r1[j] = ldw(W, (rb + 1) * HD + cb + j, f32);
      w1r2[j] = ldw(W, (rb + 2) * HD + cb + j, f32);
      w1r3[j] = ldw(W, (rb + 3) * HD + cb + j, f32);
    }
  }
  v16f w2r0, w2r1;
  {
    const int cb = 16 * s;
#pragma unroll
    for (int j = 0; j < 16; ++j) {
      w2r0[j] = ldw(Wih1, (2 * G + 0) * HD + cb + j, f32);
      w2r1[j] = ldw(Wih1, (2 * G + 1) * HD + cb + j, f32);
    }
  }
  v16f w3r0, w3r1;  // only used when !SPLIT
  const bool p3act = (tid < VC * 4);
  if constexpr (!SPLIT) {
    if (p3act) {
      const int cb = 16 * s;
#pragma unroll
      for (int j = 0; j < 16; ++j) {
        w3r0[j] = ldw(fcW, (2 * G + 0) * HD + cb + j, f32);
        w3r1[j] = ldw(fcW, (2 * G + 1) * HD + cb + j, f32);
      }
    }
  }

  v16f hc0, hc1;
#pragma unroll
  for (int j = 0; j < 16; ++j) { hc0[j] = 0.f; hc1[j] = 0.f; }

  __syncthreads();

  float* outf = (float*)out;
  __hip_bfloat16* outb = (__hip_bfloat16*)out;
  const long out_row_base = (long)b * T_LEN;

  for (int t = 0; t < T_LEN; ++t) {
    // ---- P1: rows 4g..4g+3 of (m1? Whh1·h1 : Whh0·h0), carried regs ----
    float p0 = 0.f, p1 = 0.f, p2 = 0.f, p3 = 0.f;
    if (m1 == 0) {
#pragma unroll
      for (int j = 0; j < 16; ++j) {
        const float hv = hc0[j];
        p0 += w1r0[j] * hv; p1 += w1r1[j] * hv;
        p2 += w1r2[j] * hv; p3 += w1r3[j] * hv;
      }
    } else {
#pragma unroll
      for (int j = 0; j < 16; ++j) {
        const float hv = hc1[j];
        p0 += w1r0[j] * hv; p1 += w1r1[j] * hv;
        p2 += w1r2[j] * hv; p3 += w1r3[j] * hv;
      }
    }
    // DPP reduce over 8 lanes: mirror-first (pairs s,7-s), then xor1/xor2 scatter.
    p0 += dpp_f<DPP_HALF_MIRROR>(p0);
    p1 += dpp_f<DPP_HALF_MIRROR>(p1);
    p2 += dpp_f<DPP_HALF_MIRROR>(p2);
    p3 += dpp_f<DPP_HALF_MIRROR>(p3);
    {
      const float a  = (s1b ? p2 : p0) + dpp_f<DPP_QP_XOR1>(s1b ? p0 : p2);
      const float bb = (s1b ? p3 : p1) + dpp_f<DPP_QP_XOR1>(s1b ? p1 : p3);
      const float c  = (s2b ? bb : a) + dpp_f<DPP_QP_XOR2>(s2b ? a : bb);
      if (s < 4) {
        const int row = 4 * g + permrow;
        if (m1 == 0) {
          const int xt = xrow[t];
          h0p[HPAD(row)] = tanh_fast(embp[xt * HD + row] + c);
        } else {
          r1buf[row] = c;
        }
      }
    }
    __syncthreads();  // B1: h0', r1 visible

    // ---- P2: refresh hc0 from h0'; rows 2G,2G+1 of Wih1·h0'; h1 update ----
    float h1v = 0.f;
    {
      const float4* hp = (const float4*)(h0p + 20 * s);
#pragma unroll
      for (int i = 0; i < 4; ++i) {
        const float4 v = hp[i];
        hc0[4 * i + 0] = v.x; hc0[4 * i + 1] = v.y;
        hc0[4 * i + 2] = v.z; hc0[4 * i + 3] = v.w;
      }
      float pA = 0.f, pB = 0.f;
#pragma unroll
      for (int j = 0; j < 16; ++j) {
        const float hv = hc0[j];
        pA += w2r0[j] * hv; pB += w2r1[j] * hv;
      }
      pA += dpp_f<DPP_HALF_MIRROR>(pA);
      pB += dpp_f<DPP_HALF_MIRROR>(pB);
      pA += dpp_f<DPP_QP_XOR2>(pA);
      pB += dpp_f<DPP_QP_XOR2>(pB);
      const float p = (s1b ? pB : pA) + dpp_f<DPP_QP_XOR1>(s1b ? pA : pB);
      if (s < 2) {
        const int row = 2 * G + s;
        h1v = tanh_fast(xb1[row] + r1buf[row] + p);
        h1p[HPAD(row)] = h1v;
      }
    }
    __syncthreads();  // B2: h1' visible

    if constexpr (SPLIT) {
      // hc1 carry for layer-1 waves; deferred global h1 store (drain hides in P1)
      if (m1 == 1) {
        const float4* hp = (const float4*)(h1p + 20 * s);
#pragma unroll
        for (int i = 0; i < 4; ++i) {
          const float4 v = hp[i];
          hc1[4 * i + 0] = v.x; hc1[4 * i + 1] = v.y;
          hc1[4 * i + 2] = v.z; hc1[4 * i + 3] = v.w;
        }
      }
      if (s < 2) {
        h1hist[(out_row_base + t) * HD + 2 * G + s] = h1v;
      }
    } else {
      // ---- P3 in-loop FC (fallback): refresh hc1; rows 2G,2G+1 of fcW·h1' ----
      const float4* hp = (const float4*)(h1p + 20 * s);
#pragma unroll
      for (int i = 0; i < 4; ++i) {
        const float4 v = hp[i];
        hc1[4 * i + 0] = v.x; hc1[4 * i + 1] = v.y;
        hc1[4 * i + 2] = v.z; hc1[4 * i + 3] = v.w;
      }
      if (p3act) {
        float pA = 0.f, pB = 0.f;
#pragma unroll
        for (int j = 0; j < 16; ++j) {
          const float hv = hc1[j];
          pA += w3r0[j] * hv; pB += w3r1[j] * hv;
        }
        pA += dpp_f<DPP_HALF_MIRROR>(pA);
        pB += dpp_f<DPP_HALF_MIRROR>(pB);
        pA += dpp_f<DPP_QP_XOR2>(pA);
        pB += dpp_f<DPP_QP_XOR2>(pB);
        const float p = (s1b ? pB : pA) + dpp_f<DPP_QP_XOR1>(s1b ? pA : pB);
        if (s < 2) {
          const int v3 = 2 * G + s;
          const float val = p + fcb[v3];
          const long idx = (out_row_base + t) * VC + v3;
          if (f32) outf[idx] = val; else outb[idx] = __float2bfloat16(val);
        }
      }
    }
    // no extra barrier: next P1's h0p/r1buf writes are post-B2; next P2's h1p
    // writes are post-next-B1 (after all post-B2 reads here).
  }

  if (tid < HD) {
    const long idx = HID_OFF + (long)b * HD + tid;
    const float v = h0p[HPAD(tid)];
    if (f32) outf[idx] = v; else outb[idx] = __float2bfloat16(v);
  } else if (tid < 2 * HD) {
    const int r = tid - HD;
    const long idx = HID_OFF + (long)B_SZ * HD + (long)b * HD + r;
    const float v = h1p[HPAD(r)];
    if (f32) outf[idx] = v; else outb[idx] = __float2bfloat16(v);
  }
}

// Epilogue FC: out[r][v] = sum_k h1hist[r][k]*fcW[v][k] + fcb[v].
// 2048 blocks x 256 threads; thread = (row = blk*128 + tid>>1, vh = tid&1),
// 48 outputs/thread. W from global (L2-resident, wave-broadcast addresses).
__global__ __launch_bounds__(256) void fc_epilogue(
    const float* __restrict__ h1hist,
    const void* __restrict__ fcW,
    const void* __restrict__ fcb_g,
    void* __restrict__ out) {
  const bool f32 = detect_f32(fcW);
  const long r = (long)blockIdx.x * 128 + (threadIdx.x >> 1);
  const int vh = threadIdx.x & 1;
  float acc[48];
#pragma unroll
  for (int v = 0; v < 48; ++v) acc[v] = 0.f;

  const float4* hrow = (const float4*)(h1hist + r * HD);
  if (f32) {
    const float4* W4 = (const float4*)fcW;  // [96][32] float4
#pragma unroll 2
    for (int k4 = 0; k4 < 32; ++k4) {
      const float4 h4 = hrow[k4];
#pragma unroll
      for (int v = 0; v < 48; ++v) {
        const float4 w4 = W4[(vh * 48 + v) * 32 + k4];
        acc[v] += w4.x * h4.x + w4.y * h4.y + w4.z * h4.z + w4.w * h4.w;
      }
    }
  } else {
    for (int k4 = 0; k4 < 32; ++k4) {
      const float4 h4 = hrow[k4];
#pragma unroll
      for (int v = 0; v < 48; ++v) {
        const int base = (vh * 48 + v) * HD + 4 * k4;
        acc[v] += ldw(fcW, base + 0, false) * h4.x + ldw(fcW, base + 1, false) * h4.y +
                  ldw(fcW, base + 2, false) * h4.z + ldw(fcW, base + 3, false) * h4.w;
      }
    }
  }

  if (f32) {
    float4* o = (float4*)((float*)out + r * VC + vh * 48);
#pragma unroll
    for (int i = 0; i < 12; ++i) {
      o[i] = make_float4(acc[4 * i + 0] + ldw(fcb_g, vh * 48 + 4 * i + 0, true),
                         acc[4 * i + 1] + ldw(fcb_g, vh * 48 + 4 * i + 1, true),
                         acc[4 * i + 2] + ldw(fcb_g, vh * 48 + 4 * i + 2, true),
                         acc[4 * i + 3] + ldw(fcb_g, vh * 48 + 4 * i + 3, true));
    }
  } else {
    __hip_bfloat16* o = (__hip_bfloat16*)out + r * VC + vh * 48;
#pragma unroll
    for (int v = 0; v < 48; ++v)
      o[v] = __float2bfloat16(acc[v] + ldw(fcb_g, vh * 48 + v, false));
  }
}

extern "C" void kernel_launch(void* const* d_in, const int* in_sizes, int n_in,
                              void* d_out, int out_size, void* d_ws, size_t ws_size,
                              hipStream_t stream) {
  const int* x = (const int*)d_in[0];
  const void* emb = d_in[1];
  const void* Wih0 = d_in[2];
  const void* Whh0 = d_in[3];
  const void* bih0 = d_in[4];
  const void* bhh0 = d_in[5];
  const void* Wih1 = d_in[6];
  const void* Whh1 = d_in[7];
  const void* bih1 = d_in[8];
  const void* bhh1 = d_in[9];
  const void* fcW = d_in[10];
  const void* fcb = d_in[11];

  const size_t hist_bytes = (size_t)B_SZ * T_LEN * HD * sizeof(float);  // 134.2 MB
  const size_t embp_bytes = (size_t)VC * HD * sizeof(float);            // 48 KB

  if (d_ws != nullptr && ws_size >= hist_bytes + embp_bytes) {
    float* h1hist = (float*)d_ws;
    float* embp = (float*)((char*)d_ws + hist_bytes);
    embp_kernel<<<VC, HD, 0, stream>>>(emb, Wih0, bih0, bhh0, embp);
    rnn_fused<true, true><<<B_SZ, 512, 0, stream>>>(
        x, embp, emb, Wih0, bih0, bhh0, Whh0, Wih1, Whh1, bih1, bhh1,
        fcW, fcb, h1hist, d_out);
    fc_epilogue<<<2048, 256, 0, stream>>>(h1hist, fcW, fcb, d_out);
  } else if (d_ws != nullptr && ws_size >= embp_bytes) {
    float* embp = (float*)d_ws;
    embp_kernel<<<VC, HD, 0, stream>>>(emb, Wih0, bih0, bhh0, embp);
    rnn_fused<true, false><<<B_SZ, 512, 0, stream>>>(
        x, embp, emb, Wih0, bih0, bhh0, Whh0, Wih1, Whh1, bih1, bhh1,
        fcW, fcb, nullptr, d_out);
  } else {
    rnn_fused<false, false><<<B_SZ, 512, 0, stream>>>(
        x, nullptr, emb, Wih0, bih0, bhh0, Whh0, Wih1, Whh1, bih1, bhh1,
        fcW, fcb, nullptr, d_out);
  }
}